// Round 3
// baseline (2876.481 us; speedup 1.0000x reference)
//
#include <hip/hip_runtime.h>
#include <math.h>

#define S_LEN 1024
#define BATCH 2048
#define HID   128
#define MTILE 16
#define NBLK  (BATCH / MTILE)   // 128 blocks
#define RS    136               // plane row stride in halves (16B-aligned rows, clean banks)
#define PLANE (MTILE * RS)
#define INV2048 (1.0f / 2048.0f)

typedef _Float16 half8 __attribute__((ext_vector_type(8)));
typedef _Float16 half4 __attribute__((ext_vector_type(4)));
typedef float floatx4 __attribute__((ext_vector_type(4)));

#define MFMA(a, b, c) __builtin_amdgcn_mfma_f32_16x16x32_f16((a), (b), (c), 0, 0, 0)

struct SLds {
  _Float16 spkP[2][PLANE];           // spk exact in f16
  _Float16 denH[PLANE], denL[PLANE]; // single-buffered (barrier-separated)
  _Float16 memH[2][PLANE], memL[2][PLANE];
  _Float16 bbH[2][PLANE],  bbL[2][PLANE];
  float red[4][16];
  float red2[16];
};

// 4 waves x 256 threads; wave w owns h-slice [32w, 32w+32) as TWO 16-h A-frag sets.
// Planes are [batch=16][h=128] (f16), so B-frags (states) are contiguous b128 reads
// and C-rows (consecutive h) pack into b64 writes.
__global__ __launch_bounds__(256, 1) void snn_main(
    const float* __restrict__ x, const float* __restrict__ y,
    const float* __restrict__ h0m, const float* __restrict__ h0s,
    const float* __restrict__ h0b,
    const float* __restrict__ W1x, const float* __restrict__ b1x,
    const float* __restrict__ WtauM, const float* __restrict__ btauM,
    const float* __restrict__ WtauAdp, const float* __restrict__ btauAdp,
    const float* __restrict__ Wlin, const float* __restrict__ blin,
    float* __restrict__ wsout) {
  __shared__ SLds sm;

  const int tid  = threadIdx.x;
  const int w    = tid >> 6;      // wave 0..3
  const int lane = tid & 63;
  const int c    = lane & 15;     // A-frag m (=h in slice) / B-frag n (=batch) / C col (=batch)
  const int q    = lane >> 4;     // quad
  const int bbase = blockIdx.x * MTILE;

  // ---- Register-resident weights as A-frags: A[m=c][k=q*8+j], hi/lo split.
  half8 w1h[2][4], w1l[2][4];
  half8 wtmh[2][8], wtml[2][8], wtah[2][8], wtal[2][8];
#pragma unroll
  for (int s = 0; s < 2; ++s) {
    const int hA = w * 32 + s * 16 + c;
#pragma unroll
    for (int f = 0; f < 4; ++f) {
#pragma unroll
      for (int j = 0; j < 8; ++j) {
        int k = f * 32 + q * 8 + j;
        float v = W1x[hA * 130 + 2 + k];
        _Float16 hi = (_Float16)v;
        w1h[s][f][j] = hi;
        w1l[s][f][j] = (_Float16)((v - (float)hi) * 2048.0f);
      }
    }
#pragma unroll
    for (int f = 0; f < 8; ++f) {
#pragma unroll
      for (int j = 0; j < 8; ++j) {
        int k = f * 32 + q * 8 + j;
        float vm = WtauM[hA * 256 + k];
        _Float16 hm = (_Float16)vm;
        wtmh[s][f][j] = hm;
        wtml[s][f][j] = (_Float16)((vm - (float)hm) * 2048.0f);
        float va = WtauAdp[hA * 256 + k];
        _Float16 ha = (_Float16)va;
        wtah[s][f][j] = ha;
        wtal[s][f][j] = (_Float16)((va - (float)ha) * 2048.0f);
      }
    }
  }

  // ---- Per-lane scalars at C-row h's: h = w*32 + s*16 + q*4 + r
  float b1v[8], wx0v[8], wx1v[8], btmv[8], btav[8];
#pragma unroll
  for (int s = 0; s < 2; ++s) {
#pragma unroll
    for (int r = 0; r < 4; ++r) {
      int h = w * 32 + s * 16 + q * 4 + r;
      int i = s * 4 + r;
      wx0v[i] = W1x[h * 130 + 0];
      wx1v[i] = W1x[h * 130 + 1];
      b1v[i]  = b1x[h];
      btmv[i] = btauM[h];
      btav[i] = btauAdp[h];
    }
  }

  // ---- Initial state (registers + plane buf 0)
  float memv[8], spk[8], bb[8];
#pragma unroll
  for (int s = 0; s < 2; ++s) {
    const int h0 = w * 32 + s * 16 + q * 4;
    half4 ps, mh4, ml4, bh4, bl4;
#pragma unroll
    for (int r = 0; r < 4; ++r) {
      int i = s * 4 + r;
      int gi = (bbase + c) * HID + h0 + r;
      memv[i] = h0m[gi];
      spk[i]  = h0s[gi];
      bb[i]   = h0b[gi];
      ps[r] = (_Float16)spk[i];
      float v = memv[i]; _Float16 hi = (_Float16)v;
      mh4[r] = hi; ml4[r] = (_Float16)((v - (float)hi) * 2048.0f);
      v = bb[i]; hi = (_Float16)v;
      bh4[r] = hi; bl4[r] = (_Float16)((v - (float)hi) * 2048.0f);
    }
    const int off = c * RS + h0;
    *(half4*)&sm.spkP[0][off] = ps;
    *(half4*)&sm.memH[0][off] = mh4; *(half4*)&sm.memL[0][off] = ml4;
    *(half4*)&sm.bbH[0][off]  = bh4; *(half4*)&sm.bbL[0][off]  = bl4;
  }
  float2 xcur = *(const float2*)&x[(size_t)(bbase + c) * 2];
  __syncthreads();

#pragma unroll 1
  for (int t = 0; t < S_LEN; ++t) {
    const int p = t & 1, pn = p ^ 1;
    const int bOff = c * RS + q * 8;   // B-frag base: n=c, k-chunk via f

    // ---- GEMM1: dense[h][b] = W1x_spk @ spk
    floatx4 dhh[2] = {{0.f,0.f,0.f,0.f},{0.f,0.f,0.f,0.f}};
    floatx4 dll[2] = {{0.f,0.f,0.f,0.f},{0.f,0.f,0.f,0.f}};
#pragma unroll
    for (int f = 0; f < 4; ++f) {
      half8 bs = *(const half8*)&sm.spkP[p][bOff + f * 32];
#pragma unroll
      for (int s = 0; s < 2; ++s) {
        dhh[s] = MFMA(w1h[s][f], bs, dhh[s]);
        dll[s] = MFMA(w1l[s][f], bs, dll[s]);
      }
    }
    float dense[8];
#pragma unroll
    for (int s = 0; s < 2; ++s) {
      half4 dh4, dl4;
#pragma unroll
      for (int r = 0; r < 4; ++r) {
        int i = s * 4 + r;
        float v = dhh[s][r] + dll[s][r] * INV2048 + b1v[i]
                + xcur.x * wx0v[i] + xcur.y * wx1v[i];
        dense[i] = v;
        _Float16 hi = (_Float16)v;
        dh4[r] = hi;
        dl4[r] = (_Float16)((v - (float)hi) * 2048.0f);
      }
      const int off = c * RS + w * 32 + s * 16 + q * 4;
      *(half4*)&sm.denH[off] = dh4;
      *(half4*)&sm.denL[off] = dl4;
    }
    // prefetch next x (always-valid address)
    const size_t tn = (t + 1 < S_LEN) ? (size_t)(t + 1) : (size_t)t;
    float2 xnext = *(const float2*)&x[(tn * BATCH + bbase + c) * 2];
    __syncthreads();

    // ---- GEMM2: preM = WtauM @ [den|mem], preA = WtauAdp @ [den|bb]
    floatx4 mhh[2] = {{0.f,0.f,0.f,0.f},{0.f,0.f,0.f,0.f}};
    floatx4 mll[2] = {{0.f,0.f,0.f,0.f},{0.f,0.f,0.f,0.f}};
    floatx4 ahh[2] = {{0.f,0.f,0.f,0.f},{0.f,0.f,0.f,0.f}};
    floatx4 all_[2] = {{0.f,0.f,0.f,0.f},{0.f,0.f,0.f,0.f}};
#pragma unroll
    for (int f = 0; f < 8; ++f) {
      half8 b1h_, b1l_, b2h_, b2l_;
      if (f < 4) {
        b1h_ = *(const half8*)&sm.denH[bOff + f * 32];
        b1l_ = *(const half8*)&sm.denL[bOff + f * 32];
        b2h_ = b1h_; b2l_ = b1l_;
      } else {
        const int o = bOff + (f - 4) * 32;
        b1h_ = *(const half8*)&sm.memH[p][o];
        b1l_ = *(const half8*)&sm.memL[p][o];
        b2h_ = *(const half8*)&sm.bbH[p][o];
        b2l_ = *(const half8*)&sm.bbL[p][o];
      }
#pragma unroll
      for (int s = 0; s < 2; ++s) {
        mhh[s]  = MFMA(wtmh[s][f], b1h_, mhh[s]);
        mll[s]  = MFMA(wtml[s][f], b1h_, mll[s]);
        mll[s]  = MFMA(wtmh[s][f], b1l_, mll[s]);
        ahh[s]  = MFMA(wtah[s][f], b2h_, ahh[s]);
        all_[s] = MFMA(wtal[s][f], b2h_, all_[s]);
        all_[s] = MFMA(wtah[s][f], b2l_, all_[s]);
      }
    }

    // ---- Elementwise update + packed b64 state writes
#pragma unroll
    for (int s = 0; s < 2; ++s) {
      half4 ps, mh4, ml4, bh4, bl4;
#pragma unroll
      for (int r = 0; r < 4; ++r) {
        int i = s * 4 + r;
        float preM = mhh[s][r] + mll[s][r] * INV2048 + btmv[i];
        float preA = ahh[s][r] + all_[s][r] * INV2048 + btav[i];
        float tM = __builtin_amdgcn_rcpf(1.0f + __expf(-preM));
        float tA = __builtin_amdgcn_rcpf(1.0f + __expf(-preA));
        bb[i] = tA * bb[i] + (1.0f - tA) * spk[i];
        float Bth = 0.01f + 1.8f * bb[i];
        memv[i] = memv[i] * tM + (1.0f - tM) * dense[i] - Bth * spk[i];
        spk[i] = (memv[i] - Bth) > 0.0f ? 1.0f : 0.0f;
        ps[r] = (_Float16)spk[i];
        float v = memv[i]; _Float16 hi = (_Float16)v;
        mh4[r] = hi; ml4[r] = (_Float16)((v - (float)hi) * 2048.0f);
        v = bb[i]; hi = (_Float16)v;
        bh4[r] = hi; bl4[r] = (_Float16)((v - (float)hi) * 2048.0f);
      }
      const int off = c * RS + w * 32 + s * 16 + q * 4;
      *(half4*)&sm.spkP[pn][off] = ps;
      *(half4*)&sm.memH[pn][off] = mh4; *(half4*)&sm.memL[pn][off] = ml4;
      *(half4*)&sm.bbH[pn][off]  = bh4; *(half4*)&sm.bbL[pn][off]  = bl4;
    }
    xcur = xnext;
    __syncthreads();
  }

  // ---- Readout: out[b] = mem[b,:] @ Wlin + blin; block loss partial
  float part = 0.0f;
#pragma unroll
  for (int s = 0; s < 2; ++s) {
#pragma unroll
    for (int r = 0; r < 4; ++r) {
      int h = w * 32 + s * 16 + q * 4 + r;
      part += memv[s * 4 + r] * Wlin[h];
    }
  }
  part += __shfl_xor(part, 16);
  part += __shfl_xor(part, 32);      // sum over q; every lane now has batch-c total for wave
  if (lane < 16) sm.red[w][c] = part;
  __syncthreads();
  if (tid < 16) {
    float s = sm.red[0][tid] + sm.red[1][tid] + sm.red[2][tid] + sm.red[3][tid];
    float out = s + blin[0];
    float d = out - y[bbase + tid];
    sm.red2[tid] = d * d;
  }
  __syncthreads();
  if (tid == 0) {
    float s = 0.0f;
#pragma unroll
    for (int m = 0; m < 16; ++m) s += sm.red2[m];
    wsout[blockIdx.x] = s;
  }
}

__global__ __launch_bounds__(128) void final_reduce(const float* __restrict__ ws,
                                                    float* __restrict__ out) {
  __shared__ float sh[128];
  int t = threadIdx.x;
  sh[t] = ws[t];
  __syncthreads();
  for (int s = 64; s > 0; s >>= 1) {
    if (t < s) sh[t] += sh[t + s];
    __syncthreads();
  }
  if (t == 0) out[0] = sh[0] * (1.0f / (float)BATCH);
}

extern "C" void kernel_launch(void* const* d_in, const int* in_sizes, int n_in,
                              void* d_out, int out_size, void* d_ws, size_t ws_size,
                              hipStream_t stream) {
  const float* x       = (const float*)d_in[0];
  const float* y       = (const float*)d_in[1];
  const float* h0m     = (const float*)d_in[2];
  const float* h0s     = (const float*)d_in[3];
  const float* h0b     = (const float*)d_in[4];
  const float* W1x     = (const float*)d_in[5];
  const float* b1x     = (const float*)d_in[6];
  const float* WtauM   = (const float*)d_in[7];
  const float* btauM   = (const float*)d_in[8];
  const float* WtauAdp = (const float*)d_in[9];
  const float* btauAdp = (const float*)d_in[10];
  const float* Wlin    = (const float*)d_in[11];
  const float* blin    = (const float*)d_in[12];
  float* ws = (float*)d_ws;

  snn_main<<<NBLK, 256, 0, stream>>>(x, y, h0m, h0s, h0b, W1x, b1x,
                                     WtauM, btauM, WtauAdp, btauAdp,
                                     Wlin, blin, ws);
  final_reduce<<<1, 128, 0, stream>>>(ws, (float*)d_out);
}

// Round 5
// 2694.654 us; speedup vs baseline: 1.0675x; 1.0675x over previous
//
#include <hip/hip_runtime.h>
#include <math.h>

#define S_LEN 1024
#define BATCH 2048
#define HID   128
#define MTILE 16
#define NBLK  (BATCH / MTILE)   // 128 blocks
#define INV2048 (1.0f / 2048.0f)

// ws float offsets
#define OFF_WMS  0        // [128][128]  WtauM[:, :128] @ W1x[:, 2:130]
#define OFF_WAS  16384    // [128][128]  WtauAdp[:, :128] @ W1x[:, 2:130]
#define OFF_WMX  32768    // [128][2]    WtauM_d @ W1x[:, 0:2]
#define OFF_WAX  33024    // [128][2]
#define OFF_BM   33280    // [128]       WtauM_d @ b1x + btauM
#define OFF_BA   33408    // [128]
#define OFF_PART 33536    // [128] per-block loss partials

typedef _Float16 half8 __attribute__((ext_vector_type(8)));
typedef _Float16 half4 __attribute__((ext_vector_type(4)));
typedef float floatx4 __attribute__((ext_vector_type(4)));

#define MFMA(a, b, c) __builtin_amdgcn_mfma_f32_16x16x32_f16((a), (b), (c), 0, 0, 0)

// ---- prep: fold the dense->tau linear coupling into precomputed weights ----
__global__ __launch_bounds__(128) void prep(
    const float* __restrict__ W1x, const float* __restrict__ b1x,
    const float* __restrict__ WtauM, const float* __restrict__ btauM,
    const float* __restrict__ WtauAdp, const float* __restrict__ btauAdp,
    float* __restrict__ ws) {
  const int h = blockIdx.x, k = threadIdx.x;
  float s1 = 0.f, s2 = 0.f;
  for (int d = 0; d < 128; ++d) {
    float w1 = W1x[d * 130 + 2 + k];
    s1 += WtauM[h * 256 + d] * w1;
    s2 += WtauAdp[h * 256 + d] * w1;
  }
  ws[OFF_WMS + h * 128 + k] = s1;
  ws[OFF_WAS + h * 128 + k] = s2;
  if (k < 2) {
    float a = 0.f, b = 0.f;
    for (int d = 0; d < 128; ++d) {
      a += WtauM[h * 256 + d] * W1x[d * 130 + k];
      b += WtauAdp[h * 256 + d] * W1x[d * 130 + k];
    }
    ws[OFF_WMX + h * 2 + k] = a;
    ws[OFF_WAX + h * 2 + k] = b;
  } else if (k == 2 || k == 3) {
    const float* W = (k == 2) ? WtauM : WtauAdp;
    float a = 0.f;
    for (int d = 0; d < 128; ++d) a += W[h * 256 + d] * b1x[d];
    if (k == 2) ws[OFF_BM + h] = a + btauM[h];
    else        ws[OFF_BA + h] = a + btauAdp[h];
  }
}

// Planes stored in MFMA B-fragment slab order: slab f (1 KB) holds, at
// byte (lane*16), halves B[n=lane&15][k = f*32 + (lane>>4)*8 .. +8).
// => every ds_read_b128 is lane-contiguous (fast path, no conflicts).
struct SLds {
  _Float16 spk[2][2048];
  _Float16 mH[2][2048], mL[2][2048];
  _Float16 bH[2][2048], bL[2][2048];
  float red[4][16];
  float red2[16];
};

__global__ __launch_bounds__(256, 1) void snn_main(
    const float* __restrict__ x, const float* __restrict__ y,
    const float* __restrict__ h0m, const float* __restrict__ h0s,
    const float* __restrict__ h0b,
    const float* __restrict__ W1x, const float* __restrict__ b1x,
    const float* __restrict__ WtauM, const float* __restrict__ WtauAdp,
    const float* __restrict__ Wlin, const float* __restrict__ blin,
    const float* __restrict__ ws, float* __restrict__ wsout) {
  __shared__ SLds L;

  const int tid  = threadIdx.x;
  const int w    = tid >> 6;      // wave 0..3, owns h-slice [32w, 32w+32)
  const int lane = tid & 63;
  const int c    = lane & 15;     // A-frag m (h in 16-slice) / B-frag n (batch) / C col (batch)
  const int q    = lane >> 4;
  const int bbase = blockIdx.x * MTILE;

  // ---- Register-resident A-frag weights, hi/lo split (lo pre-scaled x2048)
  half8 w1h[2][4], w1l[2][4];   // W1x[:,2:130]
  half8 msh[2][4], msl[2][4];   // WMs
  half8 wmh[2][4], wml[2][4];   // Wm  = WtauM[:,128:256]
  half8 ash[2][4], asl[2][4];   // WAs
  half8 wbh[2][4], wbl[2][4];   // Wb  = WtauAdp[:,128:256]
#pragma unroll
  for (int s = 0; s < 2; ++s) {
    const int hA = w * 32 + s * 16 + c;
#pragma unroll
    for (int f = 0; f < 4; ++f) {
#pragma unroll
      for (int j = 0; j < 8; ++j) {
        const int k = f * 32 + q * 8 + j;
        float v; _Float16 hi;
        v = W1x[hA * 130 + 2 + k]; hi = (_Float16)v;
        w1h[s][f][j] = hi; w1l[s][f][j] = (_Float16)((v - (float)hi) * 2048.0f);
        v = ws[OFF_WMS + hA * 128 + k]; hi = (_Float16)v;
        msh[s][f][j] = hi; msl[s][f][j] = (_Float16)((v - (float)hi) * 2048.0f);
        v = ws[OFF_WAS + hA * 128 + k]; hi = (_Float16)v;
        ash[s][f][j] = hi; asl[s][f][j] = (_Float16)((v - (float)hi) * 2048.0f);
        v = WtauM[hA * 256 + 128 + k]; hi = (_Float16)v;
        wmh[s][f][j] = hi; wml[s][f][j] = (_Float16)((v - (float)hi) * 2048.0f);
        v = WtauAdp[hA * 256 + 128 + k]; hi = (_Float16)v;
        wbh[s][f][j] = hi; wbl[s][f][j] = (_Float16)((v - (float)hi) * 2048.0f);
      }
    }
  }

  // ---- Per-lane scalars at this lane's C rows: h = w*32 + s*16 + q*4 + r
  float wx0v[8], wx1v[8], b1v[8], mx0[8], mx1[8], ax0[8], ax1[8], bMv[8], bAv[8];
#pragma unroll
  for (int s = 0; s < 2; ++s) {
#pragma unroll
    for (int r = 0; r < 4; ++r) {
      const int h = w * 32 + s * 16 + q * 4 + r;
      const int i = s * 4 + r;
      wx0v[i] = W1x[h * 130 + 0];
      wx1v[i] = W1x[h * 130 + 1];
      b1v[i]  = b1x[h];
      mx0[i] = ws[OFF_WMX + h * 2 + 0];
      mx1[i] = ws[OFF_WMX + h * 2 + 1];
      ax0[i] = ws[OFF_WAX + h * 2 + 0];
      ax1[i] = ws[OFF_WAX + h * 2 + 1];
      bMv[i] = ws[OFF_BM + h];
      bAv[i] = ws[OFF_BA + h];
    }
  }

  // ---- Per-lane recurrent state in C layout: (h = w*32+s*16+q*4+r, b = c)
  float memv[8], spk[8], bb[8];
#pragma unroll
  for (int s = 0; s < 2; ++s) {
#pragma unroll
    for (int r = 0; r < 4; ++r) {
      const int i = s * 4 + r;
      const int gi = (bbase + c) * HID + w * 32 + s * 16 + q * 4 + r;
      memv[i] = h0m[gi]; spk[i] = h0s[gi]; bb[i] = h0b[gi];
    }
  }

  // ---- Initialize plane buf 0 in slab order (waves split the 3 state units)
  for (int u = w; u < 3; u += 4) {
    const float* src = (u == 0) ? h0s : (u == 1) ? h0m : h0b;
#pragma unroll
    for (int f = 0; f < 4; ++f) {
      const int gbase = (bbase + c) * HID + f * 32 + q * 8;
      half8 hi8, lo8;
#pragma unroll
      for (int j = 0; j < 8; ++j) {
        float v = src[gbase + j];
        _Float16 hi = (_Float16)v;
        hi8[j] = hi; lo8[j] = (_Float16)((v - (float)hi) * 2048.0f);
      }
      const int off = f * 512 + lane * 8;
      if (u == 0) { *(half8*)&L.spk[0][off] = hi8; }
      else if (u == 1) { *(half8*)&L.mH[0][off] = hi8; *(half8*)&L.mL[0][off] = lo8; }
      else { *(half8*)&L.bH[0][off] = hi8; *(half8*)&L.bL[0][off] = lo8; }
    }
  }

  float2 xcur = *(const float2*)&x[(size_t)(bbase + c) * 2];

  // Write offsets (slab order) for this lane's C rows, per s: constant over t
  int wo[2];
#pragma unroll
  for (int s = 0; s < 2; ++s)
    wo[s] = w * 512 + ((s * 2 + (q >> 1)) * 16 + c) * 8 + (q & 1) * 4;

  __syncthreads();

#pragma unroll 1
  for (int t = 0; t < S_LEN; ++t) {
    const int p = t & 1, pn = p ^ 1;
    const int rb = lane * 8;

    floatx4 dh[2] = {{0.f,0.f,0.f,0.f},{0.f,0.f,0.f,0.f}};
    floatx4 dl[2] = {{0.f,0.f,0.f,0.f},{0.f,0.f,0.f,0.f}};
    floatx4 mh[2] = {{0.f,0.f,0.f,0.f},{0.f,0.f,0.f,0.f}};
    floatx4 ml[2] = {{0.f,0.f,0.f,0.f},{0.f,0.f,0.f,0.f}};
    floatx4 ah[2] = {{0.f,0.f,0.f,0.f},{0.f,0.f,0.f,0.f}};
    floatx4 al[2] = {{0.f,0.f,0.f,0.f},{0.f,0.f,0.f,0.f}};

#pragma unroll
    for (int f = 0; f < 4; ++f) {
      const int off = f * 512 + rb;
      half8 bs  = *(const half8*)&L.spk[p][off];
      half8 xmh = *(const half8*)&L.mH[p][off];
      half8 xml = *(const half8*)&L.mL[p][off];
      half8 xbh = *(const half8*)&L.bH[p][off];
      half8 xbl = *(const half8*)&L.bL[p][off];
#pragma unroll
      for (int s = 0; s < 2; ++s) {
        dh[s] = MFMA(w1h[s][f], bs, dh[s]);
        dl[s] = MFMA(w1l[s][f], bs, dl[s]);
        mh[s] = MFMA(msh[s][f], bs, mh[s]);
        ml[s] = MFMA(msl[s][f], bs, ml[s]);
        mh[s] = MFMA(wmh[s][f], xmh, mh[s]);
        ml[s] = MFMA(wmh[s][f], xml, ml[s]);
        ml[s] = MFMA(wml[s][f], xmh, ml[s]);
        ah[s] = MFMA(ash[s][f], bs, ah[s]);
        al[s] = MFMA(asl[s][f], bs, al[s]);
        ah[s] = MFMA(wbh[s][f], xbh, ah[s]);
        al[s] = MFMA(wbh[s][f], xbl, al[s]);
        al[s] = MFMA(wbl[s][f], xbh, al[s]);
      }
    }

    // prefetch next x (clamped address, always valid)
    const size_t tn = (t + 1 < S_LEN) ? (size_t)(t + 1) : (size_t)t;
    float2 xnext = *(const float2*)&x[(tn * BATCH + bbase + c) * 2];

    // ---- Elementwise update + packed b64 slab writes
#pragma unroll
    for (int s = 0; s < 2; ++s) {
      half4 ps, mh4, ml4, bh4, bl4;
#pragma unroll
      for (int r = 0; r < 4; ++r) {
        const int i = s * 4 + r;
        float den  = dh[s][r] + dl[s][r] * INV2048 + b1v[i]
                   + xcur.x * wx0v[i] + xcur.y * wx1v[i];
        float preM = mh[s][r] + ml[s][r] * INV2048 + bMv[i]
                   + xcur.x * mx0[i] + xcur.y * mx1[i];
        float preA = ah[s][r] + al[s][r] * INV2048 + bAv[i]
                   + xcur.x * ax0[i] + xcur.y * ax1[i];
        float tM = __builtin_amdgcn_rcpf(1.0f + __expf(-preM));
        float tA = __builtin_amdgcn_rcpf(1.0f + __expf(-preA));
        bb[i] = tA * bb[i] + (1.0f - tA) * spk[i];
        float Bth = 0.01f + 1.8f * bb[i];
        memv[i] = memv[i] * tM + (1.0f - tM) * den - Bth * spk[i];
        spk[i] = (memv[i] - Bth) > 0.0f ? 1.0f : 0.0f;
        ps[r] = (_Float16)spk[i];
        float v = memv[i]; _Float16 hi = (_Float16)v;
        mh4[r] = hi; ml4[r] = (_Float16)((v - (float)hi) * 2048.0f);
        v = bb[i]; hi = (_Float16)v;
        bh4[r] = hi; bl4[r] = (_Float16)((v - (float)hi) * 2048.0f);
      }
      *(half4*)&L.spk[pn][wo[s]] = ps;
      *(half4*)&L.mH[pn][wo[s]] = mh4; *(half4*)&L.mL[pn][wo[s]] = ml4;
      *(half4*)&L.bH[pn][wo[s]] = bh4; *(half4*)&L.bL[pn][wo[s]] = bl4;
    }
    xcur = xnext;
    __syncthreads();
  }

  // ---- Readout: out[b] = mem[b,:] @ Wlin + blin; per-block loss partial
  float part = 0.0f;
#pragma unroll
  for (int s = 0; s < 2; ++s)
#pragma unroll
    for (int r = 0; r < 4; ++r)
      part += memv[s * 4 + r] * Wlin[w * 32 + s * 16 + q * 4 + r];
  part += __shfl_xor(part, 16);
  part += __shfl_xor(part, 32);   // sum over q: lane now has wave partial for batch c
  if (lane < 16) L.red[w][c] = part;
  __syncthreads();
  if (tid < 16) {
    float s = L.red[0][tid] + L.red[1][tid] + L.red[2][tid] + L.red[3][tid];
    float out = s + blin[0];
    float d = out - y[bbase + tid];
    L.red2[tid] = d * d;
  }
  __syncthreads();
  if (tid == 0) {
    float s = 0.0f;
#pragma unroll
    for (int m = 0; m < 16; ++m) s += L.red2[m];
    wsout[OFF_PART + blockIdx.x] = s;
  }
}

__global__ __launch_bounds__(128) void final_reduce(const float* __restrict__ ws,
                                                    float* __restrict__ out) {
  __shared__ float sh[128];
  int t = threadIdx.x;
  sh[t] = ws[OFF_PART + t];
  __syncthreads();
  for (int s = 64; s > 0; s >>= 1) {
    if (t < s) sh[t] += sh[t + s];
    __syncthreads();
  }
  if (t == 0) out[0] = sh[0] * (1.0f / (float)BATCH);
}

extern "C" void kernel_launch(void* const* d_in, const int* in_sizes, int n_in,
                              void* d_out, int out_size, void* d_ws, size_t ws_size,
                              hipStream_t stream) {
  const float* x       = (const float*)d_in[0];
  const float* y       = (const float*)d_in[1];
  const float* h0m     = (const float*)d_in[2];
  const float* h0s     = (const float*)d_in[3];
  const float* h0b     = (const float*)d_in[4];
  const float* W1x     = (const float*)d_in[5];
  const float* b1x     = (const float*)d_in[6];
  const float* WtauM   = (const float*)d_in[7];
  const float* btauM   = (const float*)d_in[8];
  const float* WtauAdp = (const float*)d_in[9];
  const float* btauAdp = (const float*)d_in[10];
  const float* Wlin    = (const float*)d_in[11];
  const float* blin    = (const float*)d_in[12];
  float* ws = (float*)d_ws;

  prep<<<128, 128, 0, stream>>>(W1x, b1x, WtauM, btauM, WtauAdp, btauAdp, ws);
  snn_main<<<NBLK, 256, 0, stream>>>(x, y, h0m, h0s, h0b, W1x, b1x,
                                     WtauM, WtauAdp, Wlin, blin, ws, ws);
  final_reduce<<<1, 128, 0, stream>>>(ws, (float*)d_out);
}